// Round 10
// baseline (73.577 us; speedup 1.0000x reference)
//
#include <hip/hip_runtime.h>

#define N_ATOMS 20000
#define BATCH   16
#define N_BONDS 60000
#define NB      (N_ATOMS * BATCH)      // 320000
#define CAP     32                     // max neighbors/node (deg~Poisson(6); P(>=32)~1e-16)

#define TRANS_BLOCKS 1250   // 1250*256 = 320000 = N*B
#define DEG_BLOCKS   235    // ceil(60000/256)

// Workspace (int-indexed):
//   cnt[20000] | Mc[24]f (M 9, M2 9, K 3, pad) | adjF[20000*32] | posT[N][16] ushort4
#define OFF_CNT   0
#define OFF_MC    20000
#define OFF_ADJF  20024                       // *4 = 80096 B, %16 == 0 -> int4 OK
#define OFF_POST  (OFF_ADJF + N_ATOMS * CAP)  // 660024; *4 %8 == 0 -> ushort4 OK

// f32 <-> bf16 (RNE; data has no NaN/Inf).
__device__ __forceinline__ unsigned short f2bf(float f) {
    unsigned int u = __float_as_uint(f);
    u += 0x7FFFu + ((u >> 16) & 1u);
    return (unsigned short)(u >> 16);
}
__device__ __forceinline__ float bf2f(unsigned short h) {
    return __uint_as_float(((unsigned int)h) << 16);
}

// blocks [0,1250): transpose positions[B][N][3] -> posT[N][16] bf16x4 (b-fastest).
// blocks [1250,1485): per-edge slot fill via atomic cnt.
// block 1485: Mc = [M | M^2 | K] where M = W_msg@W_upd, c = b_msg@W_upd,
//             K = (c + b_upd)@M + 2c.
__global__ void build_kernel(const float* __restrict__ pos, const int* __restrict__ bonds,
                             const float* __restrict__ W_msg, const float* __restrict__ b_msg,
                             const float* __restrict__ W_upd, const float* __restrict__ b_upd,
                             int* __restrict__ cnt, int* __restrict__ adjF,
                             float* __restrict__ Mc, ushort4* __restrict__ posT) {
    int blk = blockIdx.x;
    if (blk < TRANS_BLOCKS) {
        int t = blk * 256 + threadIdx.x;        // 0..319999
        int b = t & 15, n = t >> 4;
        const float* p = pos + ((size_t)b * N_ATOMS + n) * 3;
        posT[n * 16 + b] = make_ushort4(f2bf(p[0]), f2bf(p[1]), f2bf(p[2]), 0);
    } else if (blk < TRANS_BLOCKS + DEG_BLOCKS) {
        int e = (blk - TRANS_BLOCKS) * 256 + threadIdx.x;
        if (e < N_BONDS) {
            int a0 = bonds[2 * e], a1 = bonds[2 * e + 1];
            int s0 = atomicAdd(&cnt[a0], 1);
            if (s0 < CAP) adjF[a0 * CAP + s0] = a1;
            int s1 = atomicAdd(&cnt[a1], 1);
            if (s1 < CAP) adjF[a1 * CAP + s1] = a0;
        }
    } else {
        __shared__ float sm[12];                // M (9), c (3)
        int t = threadIdx.x;
        if (t < 12) {
            float s = 0.0f;
            if (t < 9) {
                int i = t / 3, j = t % 3;
                for (int k = 0; k < 128; ++k) s += W_msg[i * 128 + k] * W_upd[k * 3 + j];
            } else {
                int j = t - 9;
                for (int k = 0; k < 128; ++k) s += b_msg[k] * W_upd[k * 3 + j];
            }
            sm[t] = s;
        }
        __syncthreads();
        if (t < 9) {                            // M and M^2
            int i = t / 3, j = t % 3;
            Mc[t] = sm[t];
            float s = 0.0f;
            for (int k = 0; k < 3; ++k) s += sm[i * 3 + k] * sm[k * 3 + j];
            Mc[9 + t] = s;
        } else if (t < 12) {                    // K = (c + b_upd)@M + 2c
            int j = t - 9;
            float s = 0.0f;
            for (int k = 0; k < 3; ++k) s += (sm[9 + k] + b_upd[k]) * sm[k * 3 + j];
            Mc[18 + j] = s + 2.0f * sm[9 + j];
        }
    }
}

// Single two-hop gather: h2 = h0 + inv*(2*S1@M + S2@M^2) + flag*K + 2*b_upd,
// S1 = sum_j h_j, S2 = sum_j inv_j * (sum_k h_k). Fully unrolled 8x8 predicated
// fast path (P(d<=8) ~ 84%); rare tails handled in loops. Block = 8 nodes x 16
// batches; 16 lanes/node read one 128B line per neighbor.
__global__ __launch_bounds__(128) void gather2_kernel(const ushort4* __restrict__ hT,
                                                      const int* __restrict__ cnt,
                                                      const int* __restrict__ adjF,
                                                      const float* __restrict__ Mc,
                                                      const float* __restrict__ b_upd,
                                                      float* __restrict__ outP) {
    __shared__ float lds[8 * 51];            // stride 51: conflict-free re-transpose
    int t = threadIdx.x;
    int b = t & 15;
    int nl = t >> 4;                         // 0..7
    int n = blockIdx.x * 8 + nl;             // 2500*8 = 20000 exactly
    const int4* al4 = (const int4*)(adjF + n * CAP);
    int dn = cnt[n];                         // group-uniform broadcast
    if (dn > CAP) dn = CAP;
    int4 ja = al4[0];                        // always in-bounds (CAP=32)
    int4 jb = al4[1];
    ushort4 mh = hT[n * 16 + b];
    float S1x = 0.f, S1y = 0.f, S1z = 0.f;
    float S2x = 0.f, S2y = 0.f, S2z = 0.f;
    int js[8] = {ja.x, ja.y, ja.z, ja.w, jb.x, jb.y, jb.z, jb.w};
#pragma unroll
    for (int i = 0; i < 8; ++i) {
        if (i < dn) {
            int j = js[i];
            int dj = cnt[j];
            if (dj > CAP) dj = CAP;
            const int4* jl4 = (const int4*)(adjF + j * CAP);
            int4 ka = jl4[0];
            int4 kb = jl4[1];
            ushort4 hj = hT[(size_t)j * 16 + b];
            S1x += bf2f(hj.x); S1y += bf2f(hj.y); S1z += bf2f(hj.z);
            int ks[8] = {ka.x, ka.y, ka.z, ka.w, kb.x, kb.y, kb.z, kb.w};
            float Tx = 0.f, Ty = 0.f, Tz = 0.f;
#pragma unroll
            for (int q = 0; q < 8; ++q) {
                if (q < dj) {
                    ushort4 hk = hT[(size_t)ks[q] * 16 + b];
                    Tx += bf2f(hk.x); Ty += bf2f(hk.y); Tz += bf2f(hk.z);
                }
            }
            for (int q = 8; q < dj; ++q) {   // rare inner tail
                int kk = adjF[j * CAP + q];
                ushort4 hk = hT[(size_t)kk * 16 + b];
                Tx += bf2f(hk.x); Ty += bf2f(hk.y); Tz += bf2f(hk.z);
            }
            float invj = 1.0f / (float)dj;   // dj >= 1 (j has neighbor n)
            S2x += invj * Tx; S2y += invj * Ty; S2z += invj * Tz;
        }
    }
    for (int i = 8; i < dn; ++i) {           // rare outer tail
        int j = adjF[n * CAP + i];
        int dj = cnt[j];
        if (dj > CAP) dj = CAP;
        ushort4 hj = hT[(size_t)j * 16 + b];
        S1x += bf2f(hj.x); S1y += bf2f(hj.y); S1z += bf2f(hj.z);
        float Tx = 0.f, Ty = 0.f, Tz = 0.f;
        for (int q = 0; q < dj; ++q) {
            int kk = adjF[j * CAP + q];
            ushort4 hk = hT[(size_t)kk * 16 + b];
            Tx += bf2f(hk.x); Ty += bf2f(hk.y); Tz += bf2f(hk.z);
        }
        float invj = 1.0f / (float)dj;
        S2x += invj * Tx; S2y += invj * Ty; S2z += invj * Tz;
    }
    float inv = dn > 0 ? 1.0f / (float)dn : 0.0f;
    float flag = dn > 0 ? 1.0f : 0.0f;
    float A1x = 2.f * S1x, A1y = 2.f * S1y, A1z = 2.f * S1z;
    float o0 = bf2f(mh.x) + inv * (A1x * Mc[0] + A1y * Mc[3] + A1z * Mc[6]
                                 + S2x * Mc[9] + S2y * Mc[12] + S2z * Mc[15])
             + flag * Mc[18] + 2.f * b_upd[0];
    float o1 = bf2f(mh.y) + inv * (A1x * Mc[1] + A1y * Mc[4] + A1z * Mc[7]
                                 + S2x * Mc[10] + S2y * Mc[13] + S2z * Mc[16])
             + flag * Mc[19] + 2.f * b_upd[1];
    float o2 = bf2f(mh.z) + inv * (A1x * Mc[2] + A1y * Mc[5] + A1z * Mc[8]
                                 + S2x * Mc[11] + S2y * Mc[14] + S2z * Mc[17])
             + flag * Mc[20] + 2.f * b_upd[2];
    lds[nl * 51 + b * 3 + 0] = o0;
    lds[nl * 51 + b * 3 + 1] = o1;
    lds[nl * 51 + b * 3 + 2] = o2;
    __syncthreads();
    int b2 = t >> 3, n2 = t & 7;             // remap: n fastest -> coalesced writes
    float* op = outP + ((size_t)b2 * N_ATOMS + (size_t)(blockIdx.x * 8 + n2)) * 3;
    op[0] = lds[n2 * 51 + b2 * 3 + 0];
    op[1] = lds[n2 * 51 + b2 * 3 + 1];
    op[2] = lds[n2 * 51 + b2 * 3 + 2];
}

extern "C" void kernel_launch(void* const* d_in, const int* in_sizes, int n_in,
                              void* d_out, int out_size, void* d_ws, size_t ws_size,
                              hipStream_t stream) {
    const float* positions = (const float*)d_in[0];
    const int* bonds = (const int*)d_in[1];
    const float* W_msg = (const float*)d_in[2];
    const float* b_msg = (const float*)d_in[3];
    const float* W_upd = (const float*)d_in[4];
    const float* b_upd = (const float*)d_in[5];
    float* out = (float*)d_out;

    int* wsi = (int*)d_ws;
    int* cnt = wsi + OFF_CNT;
    float* Mc = (float*)(wsi + OFF_MC);
    int* adjF = wsi + OFF_ADJF;
    ushort4* posT = (ushort4*)(wsi + OFF_POST);

    // 1. zero slot counters
    hipMemsetAsync(cnt, 0, N_ATOMS * sizeof(int), stream);
    // 2. transpose -> posT (bf16) || slot-fill adjacency || Mc (M, M^2, K)
    build_kernel<<<TRANS_BLOCKS + DEG_BLOCKS + 1, 256, 0, stream>>>(
        positions, bonds, W_msg, b_msg, W_upd, b_upd, cnt, adjF, Mc, posT);
    // 3. single two-hop gather: posT -> out[B][N][3]
    gather2_kernel<<<N_ATOMS / 8, 128, 0, stream>>>(posT, cnt, adjF, Mc, b_upd, out);
}

// Round 11
// 38.960 us; speedup vs baseline: 1.8885x; 1.8885x over previous
//
#include <hip/hip_runtime.h>

#define N_ATOMS 20000
#define BATCH   16
#define N_BONDS 60000
#define NB      (N_ATOMS * BATCH)      // 320000
#define CAP     32                     // max neighbors/node (deg~Poisson(6); P(>=32)~1e-16)

#define TRANS_BLOCKS 1250   // 1250*256 = 320000 = N*B
#define DEG_BLOCKS   235    // ceil(60000/256)
#define NGROUPS      1250   // N_ATOMS/16

// Workspace (int-indexed):
//   cnt[20000] | Mc[12]f(+pad) | adjF[20000*32] | posT[N][16] ushort4 | h2T same
#define OFF_CNT   0
#define OFF_MC    20000
#define OFF_ADJF  20016
#define OFF_POST  (OFF_ADJF + N_ATOMS * CAP)        // *4 bytes %16==0 -> aligned
#define OFF_H2T   (OFF_POST + NB * 2)               // ushort4 = 2 ints each

// f32 <-> bf16 (RNE; data has no NaN/Inf).
__device__ __forceinline__ unsigned short f2bf(float f) {
    unsigned int u = __float_as_uint(f);
    u += 0x7FFFu + ((u >> 16) & 1u);
    return (unsigned short)(u >> 16);
}
__device__ __forceinline__ float bf2f(unsigned short h) {
    return __uint_as_float(((unsigned int)h) << 16);
}

// blocks [0,1250): transpose positions[B][N][3] -> posT[N][16] bf16x4 (b-fastest,
//                  128B-contiguous per node). blocks [1250,1485): slot fill.
// block 1485: Mc = [W_msg @ W_upd ; b_msg @ W_upd].
__global__ void build_kernel(const float* __restrict__ pos, const int* __restrict__ bonds,
                             const float* __restrict__ W_msg, const float* __restrict__ b_msg,
                             const float* __restrict__ W_upd,
                             int* __restrict__ cnt, int* __restrict__ adjF,
                             float* __restrict__ Mc, ushort4* __restrict__ posT) {
    int blk = blockIdx.x;
    if (blk < TRANS_BLOCKS) {
        int t = blk * 256 + threadIdx.x;        // 0..319999
        int b = t & 15, n = t >> 4;
        const float* p = pos + ((size_t)b * N_ATOMS + n) * 3;
        posT[n * 16 + b] = make_ushort4(f2bf(p[0]), f2bf(p[1]), f2bf(p[2]), 0);
    } else if (blk < TRANS_BLOCKS + DEG_BLOCKS) {
        int e = (blk - TRANS_BLOCKS) * 256 + threadIdx.x;
        if (e < N_BONDS) {
            int a0 = bonds[2 * e], a1 = bonds[2 * e + 1];
            int s0 = atomicAdd(&cnt[a0], 1);
            if (s0 < CAP) adjF[a0 * CAP + s0] = a1;
            int s1 = atomicAdd(&cnt[a1], 1);
            if (s1 < CAP) adjF[a1 * CAP + s1] = a0;
        }
    } else {
        int t = threadIdx.x;
        if (t < 12) {
            float s = 0.0f;
            if (t < 9) {
                int i = t / 3, j = t % 3;
                for (int k = 0; k < 128; ++k) s += W_msg[i * 128 + k] * W_upd[k * 3 + j];
            } else {
                int j = t - 9;
                for (int k = 0; k < 128; ++k) s += b_msg[k] * W_upd[k * 3 + j];
            }
            Mc[t] = s;
        }
    }
}

// Node-major fused iteration, bf16 state. 16 lanes/node read one 128B line per
// neighbor. Front-loaded MLP: 2 unconditional int4 adj loads cover d<=8 (84%);
// up to 8 independent predicated gathers in flight. f32 accumulation.
// FINAL=false: d from cnt[n]; writes d into h2T.w.
// FINAL=true: d from mh.w (skips the cnt load); LDS re-transpose to out[B][N][3].
template <bool FINAL>
__global__ __launch_bounds__(256) void gather_kernel(const ushort4* __restrict__ hT,
                                                     const int* __restrict__ cnt,
                                                     const int* __restrict__ adjF,
                                                     const float* __restrict__ Mc,
                                                     const float* __restrict__ b_upd,
                                                     ushort4* __restrict__ outT,
                                                     float* __restrict__ outP) {
    __shared__ float lds[16 * 51];           // stride 51: conflict-free re-transpose
    int t = threadIdx.x;
    int b = t & 15;
    int nl = t >> 4;
    int n = blockIdx.x * 16 + nl;            // 1250*16 = 20000 exactly
    const int4* al4 = (const int4*)(adjF + n * CAP);
    int4 ja = al4[0];                        // always in-bounds (CAP=32)
    int4 jb = al4[1];
    ushort4 mh = hT[n * 16 + b];             // issued early, independent
    int d;
    if (FINAL) {
        d = (int)mh.w;                       // deg packed by gather<false>
    } else {
        int dc = cnt[n];                     // group-uniform broadcast
        d = dc > CAP ? CAP : dc;
    }
    // hoist uniform transform loads: overlap with gather latency
    float m0 = Mc[0], m1 = Mc[1], m2 = Mc[2];
    float m3 = Mc[3], m4 = Mc[4], m5 = Mc[5];
    float m6 = Mc[6], m7 = Mc[7], m8 = Mc[8];
    float c0 = Mc[9], c1 = Mc[10], c2 = Mc[11];
    float bu0 = b_upd[0], bu1 = b_upd[1], bu2 = b_upd[2];
    float sx = 0.0f, sy = 0.0f, sz = 0.0f;
#define ACC(J) { ushort4 v = hT[(size_t)(J) * 16 + b]; \
                 sx += bf2f(v.x); sy += bf2f(v.y); sz += bf2f(v.z); }
    if (0 < d) ACC(ja.x)
    if (1 < d) ACC(ja.y)
    if (2 < d) ACC(ja.z)
    if (3 < d) ACC(ja.w)
    if (4 < d) ACC(jb.x)
    if (5 < d) ACC(jb.y)
    if (6 < d) ACC(jb.z)
    if (7 < d) ACC(jb.w)
    for (int k0 = 8; k0 < d; k0 += 8) {      // rare tail (P(d>8)~15%)
        ja = al4[k0 >> 2];
        jb = al4[(k0 >> 2) + 1];
        if (k0 + 0 < d) ACC(ja.x)
        if (k0 + 1 < d) ACC(ja.y)
        if (k0 + 2 < d) ACC(ja.z)
        if (k0 + 3 < d) ACC(ja.w)
        if (k0 + 4 < d) ACC(jb.x)
        if (k0 + 5 < d) ACC(jb.y)
        if (k0 + 6 < d) ACC(jb.z)
        if (k0 + 7 < d) ACC(jb.w)
    }
#undef ACC
    float mex = bf2f(mh.x), mey = bf2f(mh.y), mez = bf2f(mh.z);
    float inv = d > 0 ? 1.0f / (float)d : 0.0f;
    float flag = d > 0 ? 1.0f : 0.0f;
    float o0 = mex + inv * (sx * m0 + sy * m3 + sz * m6) + flag * c0 + bu0;
    float o1 = mey + inv * (sx * m1 + sy * m4 + sz * m7) + flag * c1 + bu1;
    float o2 = mez + inv * (sx * m2 + sy * m5 + sz * m8) + flag * c2 + bu2;
    if (!FINAL) {
        outT[n * 16 + b] = make_ushort4(f2bf(o0), f2bf(o1), f2bf(o2), (unsigned short)d);
    } else {
        lds[nl * 51 + b * 3 + 0] = o0;
        lds[nl * 51 + b * 3 + 1] = o1;
        lds[nl * 51 + b * 3 + 2] = o2;
        __syncthreads();
        int b2 = t >> 4, n2 = t & 15;        // remap: n fastest -> coalesced writes
        float* op = outP + ((size_t)b2 * N_ATOMS + (size_t)(blockIdx.x * 16 + n2)) * 3;
        op[0] = lds[n2 * 51 + b2 * 3 + 0];
        op[1] = lds[n2 * 51 + b2 * 3 + 1];
        op[2] = lds[n2 * 51 + b2 * 3 + 2];
    }
}

extern "C" void kernel_launch(void* const* d_in, const int* in_sizes, int n_in,
                              void* d_out, int out_size, void* d_ws, size_t ws_size,
                              hipStream_t stream) {
    const float* positions = (const float*)d_in[0];
    const int* bonds = (const int*)d_in[1];
    const float* W_msg = (const float*)d_in[2];
    const float* b_msg = (const float*)d_in[3];
    const float* W_upd = (const float*)d_in[4];
    const float* b_upd = (const float*)d_in[5];
    float* out = (float*)d_out;

    int* wsi = (int*)d_ws;
    int* cnt = wsi + OFF_CNT;
    float* Mc = (float*)(wsi + OFF_MC);
    int* adjF = wsi + OFF_ADJF;
    ushort4* posT = (ushort4*)(wsi + OFF_POST);
    ushort4* h2T = (ushort4*)(wsi + OFF_H2T);

    // 1. zero slot counters (driver fill, capture-legal)
    hipMemsetAsync(cnt, 0, N_ATOMS * sizeof(int), stream);
    // 2. transpose -> posT (bf16) || slot-fill adjacency || Mc (fused by block range)
    build_kernel<<<TRANS_BLOCKS + DEG_BLOCKS + 1, 256, 0, stream>>>(
        positions, bonds, W_msg, b_msg, W_upd, cnt, adjF, Mc, posT);
    // 3. iteration 1: posT -> h2T (node-major bf16, deg packed in .w)
    gather_kernel<false><<<NGROUPS, 256, 0, stream>>>(posT, cnt, adjF, Mc, b_upd, h2T, nullptr);
    // 4. iteration 2: h2T -> out[B][N][3] f32 (LDS re-transpose)
    gather_kernel<true><<<NGROUPS, 256, 0, stream>>>(h2T, cnt, adjF, Mc, b_upd, nullptr, out);
}